// Round 2
// baseline (447.023 us; speedup 1.0000x reference)
//
#include <hip/hip_runtime.h>

// MeshVerticalLayer: out[c,b,j] = cc_mul(x[:,b,lperm[r]], diag[:,r])
//                               + cc_mul(x[:,b,lperm[p]], off[:,p]),  r=rperm[j], p=pair[r]
// x: [2,B,N] fp32, N=1024, B=32768. HBM-bound: 268MB in + 268MB out, floor ~85us.
//
// v3: T14 issue-early/write-late staging with PLAIN loads (no async builtins —
//     v2's cross-barrier global_load_lds raced). Loads for batch i+1 issue into
//     registers right after the barrier; the implicit vmcnt wait lands at the
//     ds_write at iteration end, so ~900cy HBM latency hides under the
//     gather+FMA+store phase. Double buffer, 1 barrier/iter. Keep v2's float4
//     stores (j=4t+k) and BPB=16 (grid 2048 = 8 blocks/CU).

#define NCOLS 1024
#define TPB   256
#define KPT   4          // 4 consecutive columns per thread: j = 4*t + k
#define BPB   16         // batches per block
#define NBUF  2

__global__ __launch_bounds__(TPB) void mesh_kernel(
    const float* __restrict__ x,      // [2,B,N]
    const float* __restrict__ diag,   // [2,N]
    const float* __restrict__ offd,   // [2,N]
    const int*   __restrict__ pair,   // [N]
    const int*   __restrict__ lperm,  // [N]
    const int*   __restrict__ rperm,  // [N]
    float* __restrict__ out,          // [2,B,N]
    int B)
{
    __shared__ __align__(16) float smem[NBUF][2 * NCOLS];  // 16KB

    const int t = threadIdx.x;

    // Per-column index/coefficient table (same for all batches) -> registers.
    // j = 4t+k: rperm vectorizes to one int4; rest are L1/L2-resident gathers
    // amortized over BPB batches.
    int   lr[KPT], lp[KPT];
    float d0[KPT], d1[KPT], f0[KPT], f1[KPT];
    const int4 rj = ((const int4*)rperm)[t];
    const int  rr[KPT] = {rj.x, rj.y, rj.z, rj.w};
#pragma unroll
    for (int k = 0; k < KPT; ++k) {
        const int r = rr[k];
        const int p = pair[r];
        lr[k] = lperm[r];
        lp[k] = lperm[p];
        d0[k] = diag[r];
        d1[k] = diag[NCOLS + r];
        f0[k] = offd[p];
        f1[k] = offd[NCOLS + p];
    }

    const long long BN = (long long)B * NCOLS;
    const int b0 = blockIdx.x * BPB;
    const int nb = min(BPB, B - b0);
    if (nb <= 0) return;

    const float4* g0 = (const float4*)(x + (long long)b0 * NCOLS);       // ch0 rows
    const float4* g1 = (const float4*)(x + BN + (long long)b0 * NCOLS);  // ch1 rows
    float* o0p = out + (long long)b0 * NCOLS;
    float* o1p = o0p + BN;
    const int RS4 = NCOLS / 4;   // row stride in float4s = 256

    // prologue: batch 0 -> regs -> LDS buf0 (one un-hidden load stall, once)
    float4 p0 = g0[t];
    float4 p1 = g1[t];
    ((float4*)smem[0])[t]           = p0;
    ((float4*)(smem[0] + NCOLS))[t] = p1;

    for (int i = 0; i < nb; ++i) {
        const bool pf = (i + 1 < nb);

        // Issue next batch's loads NOW (before the barrier = before compute);
        // they stay in flight until the ds_write at the bottom uses p0/p1.
        if (pf) {
            p0 = g0[(i + 1) * RS4 + t];
            p1 = g1[(i + 1) * RS4 + t];
        }

        // Makes prev iteration's ds_writes of buf[i&1] visible (lgkmcnt(0))
        // and guarantees all waves finished reading buf[(i+1)&1] last iter
        // before we overwrite it below.
        __syncthreads();

        const float* sb = smem[i & 1];
        float4 q0, q1;
        float* q0a = (float*)&q0;
        float* q1a = (float*)&q1;
#pragma unroll
        for (int k = 0; k < KPT; ++k) {
            const float a0 = sb[lr[k]];
            const float a1 = sb[NCOLS + lr[k]];
            const float e0 = sb[lp[k]];
            const float e1 = sb[NCOLS + lp[k]];
            q0a[k] = a0 * d0[k] - a1 * d1[k] + e0 * f0[k] - e1 * f1[k];
            q1a[k] = a0 * d1[k] + a1 * d0[k] + e0 * f1[k] + e1 * f0[k];
        }
        // coalesced 16B stores: wave writes 1KB contiguous per channel
        ((float4*)(o0p + (long long)i * NCOLS))[t] = q0;
        ((float4*)(o1p + (long long)i * NCOLS))[t] = q1;

        // reg -> LDS for next iteration; compiler inserts the vmcnt wait for
        // p0/p1 HERE, after the compute phase has hidden most of the latency.
        if (pf) {
            float* nbuf = smem[(i + 1) & 1];
            ((float4*)nbuf)[t]           = p0;
            ((float4*)(nbuf + NCOLS))[t] = p1;
        }
    }
}

extern "C" void kernel_launch(void* const* d_in, const int* in_sizes, int n_in,
                              void* d_out, int out_size, void* d_ws, size_t ws_size,
                              hipStream_t stream) {
    const float* x     = (const float*)d_in[0];
    const float* diag  = (const float*)d_in[1];
    const float* offd  = (const float*)d_in[2];
    const int*   pair  = (const int*)d_in[3];
    const int*   lperm = (const int*)d_in[4];
    const int*   rperm = (const int*)d_in[5];
    float* out = (float*)d_out;

    const int N = in_sizes[1] / 2;          // 1024
    const int B = in_sizes[0] / (2 * N);    // 32768
    (void)N;

    dim3 grid((B + BPB - 1) / BPB);         // 2048 blocks = 8 per CU
    mesh_kernel<<<grid, TPB, 0, stream>>>(x, diag, offd, pair, lperm, rperm, out, B);
}

// Round 4
// 432.249 us; speedup vs baseline: 1.0342x; 1.0342x over previous
//
#include <hip/hip_runtime.h>

// MeshVerticalLayer: out[c,b,j] = cc_mul(x[:,b,s0[j]], (D0,D1)[j]) + cc_mul(x[:,b,s1[j]], (F0,F1)[j])
// where s0[j]=lperm[rperm[j]], s1[j]=lperm[pair[rperm[j]]], coeffs pre-gathered by rperm/pair.
// x: [2,B,N] fp32, N=1024, B=32768. HBM-bound: 268MB in + 268MB out, floor ~85us.
//
// v5 = v4 with the nontemporal builtin type fix (ext_vector_type instead of
//      HIP_vector_type):
//     (1) fused index/coeff tables precomputed once per launch into d_ws (24KB);
//     (2) BPB=4, grid 8192 (4 block-rounds/CU) for DRAM load balancing;
//     (3) channel-interleaved LDS pairs + XOR swizzle (byte ^= ((byte>>7)&1)<<4):
//         gathers are ds_read_b64 (8 instead of 16 reads), staging writes keep
//         full 32-bank sweeps;
//     (4) nontemporal loads/stores (zero reuse on x/out).
// Fallback (ws too small): v3-style kernel with in-block setup.

#define NCOLS 1024
#define TPB   256
#define KPT   4          // j = 4*t + k
#define BPB   4          // batches per block -> grid 8192
#define NBUF  2
#define WS_BYTES (6 * NCOLS * 4)   // s0,s1 (int) + D0,D1,F0,F1 (float)

typedef float vf4 __attribute__((ext_vector_type(4)));
typedef float vf2 __attribute__((ext_vector_type(2)));
typedef int   vi4 __attribute__((ext_vector_type(4)));

// ---------------- setup kernel: fused tables into ws ----------------
__global__ __launch_bounds__(TPB) void setup_kernel(
    const float* __restrict__ diag, const float* __restrict__ offd,
    const int* __restrict__ pair, const int* __restrict__ lperm,
    const int* __restrict__ rperm, int* __restrict__ ws)
{
    const int j = blockIdx.x * TPB + threadIdx.x;
    if (j >= NCOLS) return;
    const int r = rperm[j];
    const int p = pair[r];
    int*   s0 = ws;
    int*   s1 = ws + NCOLS;
    float* cf = (float*)(ws + 2 * NCOLS);   // D0 | D1 | F0 | F1
    s0[j]             = lperm[r];
    s1[j]             = lperm[p];
    cf[j]             = diag[r];
    cf[NCOLS + j]     = diag[NCOLS + r];
    cf[2 * NCOLS + j] = offd[p];
    cf[3 * NCOLS + j] = offd[NCOLS + p];
}

// LDS swizzle: flip bit4 by bit7. Bijective, keeps 8B/16B alignment.
// Staged b128 writes (32B/lane stride) regain full 32-bank sweeps; gather
// reads are random-addressed so unaffected on average.
__device__ __forceinline__ int swz(int byteoff) {
    return byteoff ^ (((byteoff >> 7) & 1) << 4);
}

// ---------------- main kernel ----------------
__global__ __launch_bounds__(TPB) void mesh_kernel(
    const float* __restrict__ x,      // [2,B,N]
    const int*   __restrict__ ws,     // fused tables
    float* __restrict__ out,          // [2,B,N]
    int B)
{
    // pairs (ch0,ch1) per column: 8B * 1024 = 8KB per batch, double-buffered
    __shared__ __align__(16) char smem[NBUF][8 * NCOLS];   // 16KB

    const int t = threadIdx.x;

    // table setup: 6 coalesced vector loads (ws is L2-hot, 24KB)
    const vi4 s0v = ((const vi4*)ws)[t];
    const vi4 s1v = ((const vi4*)(ws + NCOLS))[t];
    const float* cf = (const float*)(ws + 2 * NCOLS);
    const vf4 D0 = ((const vf4*)cf)[t];
    const vf4 D1 = ((const vf4*)(cf + NCOLS))[t];
    const vf4 F0 = ((const vf4*)(cf + 2 * NCOLS))[t];
    const vf4 F1 = ((const vf4*)(cf + 3 * NCOLS))[t];

    const long long BN = (long long)B * NCOLS;
    const int b0 = blockIdx.x * BPB;
    const int nb = min(BPB, B - b0);
    if (nb <= 0) return;

    const vf4* g0 = (const vf4*)(x + (long long)b0 * NCOLS);
    const vf4* g1 = (const vf4*)(x + BN + (long long)b0 * NCOLS);
    float* o0p = out + (long long)b0 * NCOLS;
    float* o1p = o0p + BN;
    const int RS4 = NCOLS / 4;

    // prologue: batch 0 -> regs -> interleaved/swizzled LDS buf0
    vf4 p0 = __builtin_nontemporal_load(g0 + t);
    vf4 p1 = __builtin_nontemporal_load(g1 + t);
    {
        char* sb = smem[0];
        vf4 w0; w0.x = p0.x; w0.y = p1.x; w0.z = p0.y; w0.w = p1.y;
        vf4 w1; w1.x = p0.z; w1.y = p1.z; w1.z = p0.w; w1.w = p1.w;
        *(vf4*)(sb + swz(32 * t))      = w0;
        *(vf4*)(sb + swz(32 * t + 16)) = w1;
    }

    for (int i = 0; i < nb; ++i) {
        const bool pf = (i + 1 < nb);
        // T14: issue next batch's loads before the barrier/compute
        if (pf) {
            p0 = __builtin_nontemporal_load(g0 + (i + 1) * RS4 + t);
            p1 = __builtin_nontemporal_load(g1 + (i + 1) * RS4 + t);
        }
        // drains prev ds_writes (lgkmcnt) and prior reads of the buffer the
        // epilogue below overwrites
        __syncthreads();

        const char* sb = smem[i & 1];
        vf4 q0, q1;
#pragma unroll
        for (int k = 0; k < KPT; ++k) {
            const int lrk = (k == 0) ? s0v.x : (k == 1) ? s0v.y : (k == 2) ? s0v.z : s0v.w;
            const int lpk = (k == 0) ? s1v.x : (k == 1) ? s1v.y : (k == 2) ? s1v.z : s1v.w;
            const float d0k = (k == 0) ? D0.x : (k == 1) ? D0.y : (k == 2) ? D0.z : D0.w;
            const float d1k = (k == 0) ? D1.x : (k == 1) ? D1.y : (k == 2) ? D1.z : D1.w;
            const float f0k = (k == 0) ? F0.x : (k == 1) ? F0.y : (k == 2) ? F0.z : F0.w;
            const float f1k = (k == 0) ? F1.x : (k == 1) ? F1.y : (k == 2) ? F1.z : F1.w;
            const vf2 a = *(const vf2*)(sb + swz(8 * lrk));  // (ch0,ch1)
            const vf2 e = *(const vf2*)(sb + swz(8 * lpk));
            const float r0 = a.x * d0k - a.y * d1k + e.x * f0k - e.y * f1k;
            const float r1 = a.x * d1k + a.y * d0k + e.x * f1k + e.y * f0k;
            if (k == 0) { q0.x = r0; q1.x = r1; }
            else if (k == 1) { q0.y = r0; q1.y = r1; }
            else if (k == 2) { q0.z = r0; q1.z = r1; }
            else { q0.w = r0; q1.w = r1; }
        }
        // coalesced 16B nontemporal stores (1KB contiguous per wave/channel)
        __builtin_nontemporal_store(q0, (vf4*)(o0p + (long long)i * NCOLS) + t);
        __builtin_nontemporal_store(q1, (vf4*)(o1p + (long long)i * NCOLS) + t);

        // reg -> LDS for next iteration (vmcnt wait for p0/p1 lands here)
        if (pf) {
            char* nbf = smem[(i + 1) & 1];
            vf4 w0; w0.x = p0.x; w0.y = p1.x; w0.z = p0.y; w0.w = p1.y;
            vf4 w1; w1.x = p0.z; w1.y = p1.z; w1.z = p0.w; w1.w = p1.w;
            *(vf4*)(nbf + swz(32 * t))      = w0;
            *(vf4*)(nbf + swz(32 * t + 16)) = w1;
        }
    }
}

// ---------------- fallback (ws unavailable): v3 structure ----------------
#define FB_BPB 16
__global__ __launch_bounds__(TPB) void mesh_kernel_fb(
    const float* __restrict__ x, const float* __restrict__ diag,
    const float* __restrict__ offd, const int* __restrict__ pair,
    const int* __restrict__ lperm, const int* __restrict__ rperm,
    float* __restrict__ out, int B)
{
    __shared__ __align__(16) float smem[NBUF][2 * NCOLS];
    const int t = threadIdx.x;
    int   lr[KPT], lp[KPT];
    float d0[KPT], d1[KPT], f0[KPT], f1[KPT];
    const int4 rj = ((const int4*)rperm)[t];
    const int  rr[KPT] = {rj.x, rj.y, rj.z, rj.w};
#pragma unroll
    for (int k = 0; k < KPT; ++k) {
        const int r = rr[k];
        const int p = pair[r];
        lr[k] = lperm[r];  lp[k] = lperm[p];
        d0[k] = diag[r];   d1[k] = diag[NCOLS + r];
        f0[k] = offd[p];   f1[k] = offd[NCOLS + p];
    }
    const long long BN = (long long)B * NCOLS;
    const int b0 = blockIdx.x * FB_BPB;
    const int nb = min(FB_BPB, B - b0);
    if (nb <= 0) return;
    const float4* g0 = (const float4*)(x + (long long)b0 * NCOLS);
    const float4* g1 = (const float4*)(x + BN + (long long)b0 * NCOLS);
    float* o0p = out + (long long)b0 * NCOLS;
    float* o1p = o0p + BN;
    const int RS4 = NCOLS / 4;
    float4 p0 = g0[t];
    float4 p1 = g1[t];
    ((float4*)smem[0])[t]           = p0;
    ((float4*)(smem[0] + NCOLS))[t] = p1;
    for (int i = 0; i < nb; ++i) {
        const bool pf = (i + 1 < nb);
        if (pf) { p0 = g0[(i + 1) * RS4 + t]; p1 = g1[(i + 1) * RS4 + t]; }
        __syncthreads();
        const float* sb = smem[i & 1];
        float4 q0, q1;
        float* q0a = (float*)&q0;
        float* q1a = (float*)&q1;
#pragma unroll
        for (int k = 0; k < KPT; ++k) {
            const float a0 = sb[lr[k]];
            const float a1 = sb[NCOLS + lr[k]];
            const float e0 = sb[lp[k]];
            const float e1 = sb[NCOLS + lp[k]];
            q0a[k] = a0 * d0[k] - a1 * d1[k] + e0 * f0[k] - e1 * f1[k];
            q1a[k] = a0 * d1[k] + a1 * d0[k] + e0 * f1[k] + e1 * f0[k];
        }
        ((float4*)(o0p + (long long)i * NCOLS))[t] = q0;
        ((float4*)(o1p + (long long)i * NCOLS))[t] = q1;
        if (pf) {
            float* nbf = smem[(i + 1) & 1];
            ((float4*)nbf)[t]           = p0;
            ((float4*)(nbf + NCOLS))[t] = p1;
        }
    }
}

extern "C" void kernel_launch(void* const* d_in, const int* in_sizes, int n_in,
                              void* d_out, int out_size, void* d_ws, size_t ws_size,
                              hipStream_t stream) {
    const float* x     = (const float*)d_in[0];
    const float* diag  = (const float*)d_in[1];
    const float* offd  = (const float*)d_in[2];
    const int*   pair  = (const int*)d_in[3];
    const int*   lperm = (const int*)d_in[4];
    const int*   rperm = (const int*)d_in[5];
    float* out = (float*)d_out;

    const int N = in_sizes[1] / 2;          // 1024
    const int B = in_sizes[0] / (2 * N);    // 32768
    (void)N;

    if (d_ws != nullptr && ws_size >= (size_t)WS_BYTES) {
        int* ws = (int*)d_ws;
        setup_kernel<<<dim3(NCOLS / TPB), TPB, 0, stream>>>(diag, offd, pair,
                                                            lperm, rperm, ws);
        dim3 grid((B + BPB - 1) / BPB);     // 8192 blocks
        mesh_kernel<<<grid, TPB, 0, stream>>>(x, ws, out, B);
    } else {
        dim3 grid((B + FB_BPB - 1) / FB_BPB);
        mesh_kernel_fb<<<grid, TPB, 0, stream>>>(x, diag, offd, pair, lperm,
                                                 rperm, out, B);
    }
}